// Round 8
// baseline (7390.292 us; speedup 1.0000x reference)
//
#include <hip/hip_runtime.h>

#define B_ 256
#define T_ 512
#define I_ 128
#define H_ 256
#define C_ 1000

#define RSTR 17   // fc reduction row stride (16-float rows)
#define RSTR2 33  // lstm reduction row stride (32-float rows), odd -> 2-way banks

// workspace layout (floats):
//   0        h0t[2][H*B]   (TRANSPOSED hidden: ht[hidx][batch])
//   131072   h1t[2][H*B]
//   262144   c0[B*H]       (cell state, batch-major)
//   327680   c1[B*H]
//   393216   Wt_ih0 [128][1024]   (k-major transpose of Wih0)
//   524288   Wt_hh0 [256][1024]
//   786432   Wt_ih1 [256][1024]
//   1048576  Wt_hh1 [256][1024]
#define WT_OFF   393216
#define WT_FLOATS 917504
#define WS_NEED_FLOATS (WT_OFF + WT_FLOATS)

__device__ __forceinline__ float fsig(float x) { return 1.0f / (1.0f + __expf(-x)); }
__device__ __forceinline__ float ftanh(float x) { return 2.0f / (1.0f + __expf(-2.0f * x)) - 1.0f; }

// one-time: transpose the 4 weight matrices into k-major Wt[k][1024] (proven)
__global__ __launch_bounds__(256) void transpose_w(
    const float* __restrict__ Wih0, const float* __restrict__ Whh0,
    const float* __restrict__ Wih1, const float* __restrict__ Whh1,
    float* __restrict__ ws)
{
    int idx = blockIdx.x * 256 + threadIdx.x;
    float* wt = ws + WT_OFF;
    if (idx < 131072) { int k = idx >> 10, r = idx & 1023; wt[idx] = Wih0[r * I_ + k]; return; }
    idx -= 131072; wt += 131072;
    if (idx < 262144) { int k = idx >> 10, r = idx & 1023; wt[idx] = Whh0[r * H_ + k]; return; }
    idx -= 262144; wt += 262144;
    if (idx < 262144) { int k = idx >> 10, r = idx & 1023; wt[idx] = Wih1[r * H_ + k]; return; }
    idx -= 262144; wt += 262144;
    { int k = idx >> 10, r = idx & 1023; wt[idx] = Whh1[r * H_ + k]; }
}

// ---------------------------------------------------------------------------
// Per-step kernel v4 = r6 (6841us) + T14 async-STAGE split:
//   per chunk: ds_write(cc from regs) -> barrier -> ISSUE global loads(cc+1)
//              -> compute(cc) -> barrier
// Global L2/L3 staging latency (h written by the previous step's kernel on
// other XCDs) now overlaps the compute phase instead of sitting before the
// barrier. All addresses, LDS layout, inner loop and FP order identical to
// r6 -> bitwise-identical output expected.
// ---------------------------------------------------------------------------
__global__ __launch_bounds__(256) void lstm_step_t4(
    const float* __restrict__ x,
    const float* __restrict__ bih0, const float* __restrict__ bhh0,
    const float* __restrict__ bih1, const float* __restrict__ bhh1,
    float* __restrict__ ws, int s)
{
    __shared__ float lds[2 * 128 * 36];
    float* As  = lds;               // A: [k][36] (32 batches + pad)
    float* Wsh = lds + 128 * 36;    // W: [k][36] (32 gate cols + pad)

    float* h0t = ws;                 // [2][H*B] transposed
    float* h1t = ws + 2 * B_ * H_;   // [2][H*B] transposed
    float* c0 = ws + 4 * B_ * H_;
    float* c1 = ws + 5 * B_ * H_;

    const int w = blockIdx.x;
    const int layer = w >> 8;
    const int r = w & 255;
    const int bb = r >> 5;   // batch block (8 of 32)
    const int hb = r & 31;   // h block (32 of 8 h-indices -> 32 gate cols)

    if (layer == 0 && s >= T_) return;
    if (layer == 1 && s < 1) return;
    const int t = (layer == 0) ? s : (s - 1);

    const float* hprev_t; const float* h0cur_t = nullptr;
    float* hout_t; float* cbuf;
    const float* bi; const float* bh;
    const float* wt_ih; const float* wt_hh;
    int nchunks;
    if (layer == 0) {
        hprev_t = h0t + ((t - 1) & 1) * B_ * H_;
        hout_t  = h0t + (t & 1) * B_ * H_;
        cbuf = c0; bi = bih0; bh = bhh0;
        wt_ih = ws + WT_OFF;            // [128][1024]
        wt_hh = ws + WT_OFF + 131072;   // [256][1024]
        nchunks = 3;   // K = 128 (x) + 256 (h0prev)
    } else {
        h0cur_t = h0t + (t & 1) * B_ * H_;
        hprev_t = h1t + ((t - 1) & 1) * B_ * H_;
        hout_t  = h1t + (t & 1) * B_ * H_;
        cbuf = c1; bi = bih1; bh = bhh1;
        wt_ih = ws + WT_OFF + 393216;   // [256][1024]
        wt_hh = ws + WT_OFF + 655360;   // [256][1024]
        nchunks = 4;   // K = 256 (h0cur) + 256 (h1prev)
    }

    const int tid = threadIdx.x;
    const int srow = tid >> 3;   // x-chunk scalar staging row 0..31
    const int kv = tid & 7;
    const int wave = tid >> 6;
    const int lane = tid & 63;
    const int sub = lane >> 5;   // k-subslice 0..1 (16 k each)
    const int pos = lane & 31;
    const int br4 = pos >> 3;    // batch group 0..3 (batches br4*8..+7)
    const int gc = pos & 7;      // gate-col group 0..7 (cols gc*4..+3)
    const int kbase = wave * 32 + sub * 16;   // this thread's k window base
    const int krow = tid >> 1;   // fast-staging k-row 0..127
    const int half = tid & 1;

    float4 ra0, ra1, ra2, ra3;   // A chunk in flight
    float4 rw0, rw1, rw2, rw3;   // W chunk in flight

    // ---- load chunk cc's A into ra*, W into rw* (global issue only) ----
    auto load_chunk = [&](int cc) {
        if (layer == 0 && cc == 0) {
            const float* ap = x + ((size_t)(bb * 32 + srow) * T_ + t) * I_;
            ra0 = *(const float4*)(ap + (kv +  0) * 4);
            ra1 = *(const float4*)(ap + (kv +  8) * 4);
            ra2 = *(const float4*)(ap + (kv + 16) * 4);
            ra3 = *(const float4*)(ap + (kv + 24) * 4);
        } else {
            const float* hsrc; int k0;
            if (layer == 0) { hsrc = hprev_t; k0 = (cc - 1) * 128; }
            else if (cc < 2) { hsrc = h0cur_t; k0 = cc * 128; }
            else             { hsrc = hprev_t; k0 = (cc - 2) * 128; }
            const float* asrc = hsrc + (size_t)(k0 + krow) * B_ + bb * 32 + half * 16;
            ra0 = ((const float4*)asrc)[0];
            ra1 = ((const float4*)asrc)[1];
            ra2 = ((const float4*)asrc)[2];
            ra3 = ((const float4*)asrc)[3];
        }
        {
            const float* wtc; int k0w;
            if (layer == 0) {
                if (cc == 0) { wtc = wt_ih; k0w = 0; }
                else         { wtc = wt_hh; k0w = (cc - 1) * 128; }
            } else {
                if (cc < 2)  { wtc = wt_ih; k0w = cc * 128; }
                else         { wtc = wt_hh; k0w = (cc - 2) * 128; }
            }
            const float* wsrc = wtc + (size_t)(k0w + krow) * 1024 + hb * 8;
            const float* s0 = wsrc + (2 * half) * 256;
            const float* s1 = wsrc + (2 * half + 1) * 256;
            rw0 = ((const float4*)s0)[0];
            rw1 = ((const float4*)s0)[1];
            rw2 = ((const float4*)s1)[0];
            rw3 = ((const float4*)s1)[1];
        }
    };

    // ---- write chunk cc (held in ra*/rw*) into LDS ----
    auto write_chunk = [&](int cc) {
        if (layer == 0 && cc == 0) {
            const int k0 = (kv +  0) * 4;
            As[(k0 + 0) * 36 + srow] = ra0.x;
            As[(k0 + 1) * 36 + srow] = ra0.y;
            As[(k0 + 2) * 36 + srow] = ra0.z;
            As[(k0 + 3) * 36 + srow] = ra0.w;
            const int k1 = (kv +  8) * 4;
            As[(k1 + 0) * 36 + srow] = ra1.x;
            As[(k1 + 1) * 36 + srow] = ra1.y;
            As[(k1 + 2) * 36 + srow] = ra1.z;
            As[(k1 + 3) * 36 + srow] = ra1.w;
            const int k2 = (kv + 16) * 4;
            As[(k2 + 0) * 36 + srow] = ra2.x;
            As[(k2 + 1) * 36 + srow] = ra2.y;
            As[(k2 + 2) * 36 + srow] = ra2.z;
            As[(k2 + 3) * 36 + srow] = ra2.w;
            const int k3 = (kv + 24) * 4;
            As[(k3 + 0) * 36 + srow] = ra3.x;
            As[(k3 + 1) * 36 + srow] = ra3.y;
            As[(k3 + 2) * 36 + srow] = ra3.z;
            As[(k3 + 3) * 36 + srow] = ra3.w;
        } else {
            float* adst = As + krow * 36 + half * 16;
            ((float4*)adst)[0] = ra0;
            ((float4*)adst)[1] = ra1;
            ((float4*)adst)[2] = ra2;
            ((float4*)adst)[3] = ra3;
        }
        float* wdst = Wsh + krow * 36 + half * 16;
        ((float4*)wdst)[0] = rw0;
        ((float4*)wdst)[1] = rw1;
        ((float4*)wdst)[2] = rw2;
        ((float4*)wdst)[3] = rw3;
    };

    float acc[8][4];
#pragma unroll
    for (int a = 0; a < 8; ++a)
#pragma unroll
        for (int b = 0; b < 4; ++b) acc[a][b] = 0.0f;

    load_chunk(0);
    for (int cc = 0; cc < nchunks; ++cc) {
        write_chunk(cc);
        __syncthreads();
        if (cc + 1 < nchunks) load_chunk(cc + 1);   // in flight during compute
        // ---- compute: 8x4 per thread over 16-k subslice (verbatim r6) ----
        const float* Ap = &As[kbase * 36 + br4 * 8];
        const float* Wp = &Wsh[kbase * 36 + gc * 4];
#pragma unroll
        for (int kk = 0; kk < 16; ++kk) {
            float4 a0 = *(const float4*)(Ap + kk * 36);
            float4 a1 = *(const float4*)(Ap + kk * 36 + 4);
            float4 wv = *(const float4*)(Wp + kk * 36);
            acc[0][0] += a0.x * wv.x; acc[0][1] += a0.x * wv.y; acc[0][2] += a0.x * wv.z; acc[0][3] += a0.x * wv.w;
            acc[1][0] += a0.y * wv.x; acc[1][1] += a0.y * wv.y; acc[1][2] += a0.y * wv.z; acc[1][3] += a0.y * wv.w;
            acc[2][0] += a0.z * wv.x; acc[2][1] += a0.z * wv.y; acc[2][2] += a0.z * wv.z; acc[2][3] += a0.z * wv.w;
            acc[3][0] += a0.w * wv.x; acc[3][1] += a0.w * wv.y; acc[3][2] += a0.w * wv.z; acc[3][3] += a0.w * wv.w;
            acc[4][0] += a1.x * wv.x; acc[4][1] += a1.x * wv.y; acc[4][2] += a1.x * wv.z; acc[4][3] += a1.x * wv.w;
            acc[5][0] += a1.y * wv.x; acc[5][1] += a1.y * wv.y; acc[5][2] += a1.y * wv.z; acc[5][3] += a1.y * wv.w;
            acc[6][0] += a1.z * wv.x; acc[6][1] += a1.z * wv.y; acc[6][2] += a1.z * wv.z; acc[6][3] += a1.z * wv.w;
            acc[7][0] += a1.w * wv.x; acc[7][1] += a1.w * wv.y; acc[7][2] += a1.w * wv.z; acc[7][3] += a1.w * wv.w;
        }
        __syncthreads();
    }

    // cross-slice reduction via LDS (verbatim r6)
    float* red = lds;   // 256*33 = 8448 <= 9216 floats
    {
        const int rbase = tid * RSTR2;
#pragma unroll
        for (int a = 0; a < 8; ++a)
#pragma unroll
            for (int b = 0; b < 4; ++b)
                red[rbase + a * 4 + b] = acc[a][b];
    }
    __syncthreads();
    {
        const int bl = tid >> 3;  // local batch 0..31
        const int j = tid & 7;    // local h-index 0..7
        float g4[4];
#pragma unroll
        for (int g = 0; g < 4; ++g) {
            const int col = g * 8 + j;           // local gate col 0..31
            const int tbase = (bl >> 3) * 8 + (col >> 2);   // pos of owner
            const int off = (bl & 7) * 4 + (col & 3);
            float v = 0.0f;
#pragma unroll
            for (int wv = 0; wv < 4; ++wv) {
                v += red[(wv * 64 +      tbase) * RSTR2 + off];   // sub 0: k 0..15
                v += red[(wv * 64 + 32 + tbase) * RSTR2 + off];   // sub 1: k 16..31
            }
            const int growg = g * H_ + hb * 8 + j;
            v += bi[growg] + bh[growg];
            g4[g] = v;
        }
        const float ig = fsig(g4[0]);
        const float fg = fsig(g4[1]);
        const float gg = ftanh(g4[2]);
        const float og = fsig(g4[3]);
        const int b = bb * 32 + bl;
        const int hidx = hb * 8 + j;
        const int ci = b * H_ + hidx;             // c stays batch-major
        const float cn = fg * cbuf[ci] + ig * gg;
        cbuf[ci] = cn;
        hout_t[(size_t)hidx * B_ + b] = og * ftanh(cn);   // h stored TRANSPOSED
    }
}

// fc over transposed h1: h1t[hidx][batch] (verbatim r4-proven)
__global__ __launch_bounds__(256) void fc_kernel_t(
    const float* __restrict__ ws, const float* __restrict__ fcW,
    const float* __restrict__ fcb, float* __restrict__ out)
{
    __shared__ float As[128 * 36];
    __shared__ float Wsh[128 * 36];

    const float* h1 = ws + 3 * B_ * H_;  // h1t[(T-1)&1] = h1t[1]
    const int bb = blockIdx.x >> 5;
    const int cb = blockIdx.x & 31;
    const int tid = threadIdx.x;
    const int srow = tid >> 3;
    const int kv = tid & 7;
    const int wave = tid >> 6;
    const int lane = tid & 63;
    const int br = lane >> 3;
    const int gc8 = lane & 7;
    const int crow = cb * 32 + srow;
    const int krow = tid >> 1;
    const int half = tid & 1;

    float acc[4][4];
#pragma unroll
    for (int a = 0; a < 4; ++a)
#pragma unroll
        for (int b = 0; b < 4; ++b) acc[a][b] = 0.0f;

    for (int cc = 0; cc < 2; ++cc) {
        {
            const float* asrc = h1 + (size_t)(cc * 128 + krow) * B_ + bb * 32 + half * 16;
            float4 a0 = ((const float4*)asrc)[0];
            float4 a1 = ((const float4*)asrc)[1];
            float4 a2 = ((const float4*)asrc)[2];
            float4 a3 = ((const float4*)asrc)[3];
            float* adst = As + krow * 36 + half * 16;
            ((float4*)adst)[0] = a0;
            ((float4*)adst)[1] = a1;
            ((float4*)adst)[2] = a2;
            ((float4*)adst)[3] = a3;
        }
#pragma unroll
        for (int i = 0; i < 4; ++i) {
            const int k4 = (kv + 8 * i) * 4;
            float4 vw = make_float4(0.f, 0.f, 0.f, 0.f);
            if (crow < C_) vw = *(const float4*)(fcW + crow * H_ + cc * 128 + k4);
            Wsh[(k4 + 0) * 36 + srow] = vw.x;
            Wsh[(k4 + 1) * 36 + srow] = vw.y;
            Wsh[(k4 + 2) * 36 + srow] = vw.z;
            Wsh[(k4 + 3) * 36 + srow] = vw.w;
        }
        __syncthreads();
        const float* Ap = &As[(wave * 32) * 36 + br * 4];
        const float* Wp = &Wsh[(wave * 32) * 36 + gc8 * 4];
#pragma unroll
        for (int kk = 0; kk < 32; ++kk) {
            float4 a = *(const float4*)(Ap + kk * 36);
            float4 wv = *(const float4*)(Wp + kk * 36);
            acc[0][0] += a.x * wv.x; acc[0][1] += a.x * wv.y; acc[0][2] += a.x * wv.z; acc[0][3] += a.x * wv.w;
            acc[1][0] += a.y * wv.x; acc[1][1] += a.y * wv.y; acc[1][2] += a.y * wv.z; acc[1][3] += a.y * wv.w;
            acc[2][0] += a.z * wv.x; acc[2][1] += a.z * wv.y; acc[2][2] += a.z * wv.z; acc[2][3] += a.z * wv.w;
            acc[3][0] += a.w * wv.x; acc[3][1] += a.w * wv.y; acc[3][2] += a.w * wv.z; acc[3][3] += a.w * wv.w;
        }
        __syncthreads();
    }

    float* red = As;
    {
        const int base = tid * RSTR;
#pragma unroll
        for (int a = 0; a < 4; ++a)
#pragma unroll
            for (int b = 0; b < 4; ++b)
                red[base + a * 4 + b] = acc[a][b];
    }
    __syncthreads();
    {
        const int bl = tid >> 3;
        const int j = tid & 7;
#pragma unroll
        for (int g = 0; g < 4; ++g) {
            const int gc = g * 8 + j;
            const int br2 = bl >> 2, bi2 = bl & 3, gq = gc >> 2, gj = gc & 3;
            float v = 0.0f;
#pragma unroll
            for (int wv = 0; wv < 4; ++wv)
                v += red[(wv * 64 + br2 * 8 + gq) * RSTR + bi2 * 4 + gj];
            const int cglob = cb * 32 + gc;
            if (cglob < C_) {
                v += fcb[cglob];
                out[(size_t)(bb * 32 + bl) * C_ + cglob] = v;
            }
        }
    }
}

// ---------------------------------------------------------------------------
// Fallback pair (proven 7472us path, batch-major h) if ws is too small.
// ---------------------------------------------------------------------------
__global__ __launch_bounds__(256) void lstm_step(
    const float* __restrict__ x,
    const float* __restrict__ Wih0, const float* __restrict__ Whh0,
    const float* __restrict__ bih0, const float* __restrict__ bhh0,
    const float* __restrict__ Wih1, const float* __restrict__ Whh1,
    const float* __restrict__ bih1, const float* __restrict__ bhh1,
    float* __restrict__ ws, int s)
{
    __shared__ float As[128 * 36];
    __shared__ float Wsh[128 * 36];

    float* h0buf = ws;
    float* h1buf = ws + 2 * B_ * H_;
    float* c0 = ws + 4 * B_ * H_;
    float* c1 = ws + 5 * B_ * H_;

    const int w = blockIdx.x;
    const int layer = w >> 8;
    const int r = w & 255;
    const int bb = r >> 5;
    const int hb = r & 31;

    if (layer == 0 && s >= T_) return;
    if (layer == 1 && s < 1) return;
    const int t = (layer == 0) ? s : (s - 1);

    const float* hprev; const float* h0cur = nullptr;
    float* hout; float* cbuf;
    const float* Wih; const float* Whh; const float* bi; const float* bh;
    int nchunks;
    if (layer == 0) {
        hprev = h0buf + ((t - 1) & 1) * B_ * H_;
        hout  = h0buf + (t & 1) * B_ * H_;
        cbuf = c0; Wih = Wih0; Whh = Whh0; bi = bih0; bh = bhh0;
        nchunks = 3;
    } else {
        h0cur = h0buf + (t & 1) * B_ * H_;
        hprev = h1buf + ((t - 1) & 1) * B_ * H_;
        hout  = h1buf + (t & 1) * B_ * H_;
        cbuf = c1; Wih = Wih1; Whh = Whh1; bi = bih1; bh = bhh1;
        nchunks = 4;
    }

    const int tid = threadIdx.x;
    const int srow = tid >> 3;
    const int kv = tid & 7;
    const int wave = tid >> 6;
    const int lane = tid & 63;
    const int br = lane >> 3;
    const int gc8 = lane & 7;
    const int grow = (srow >> 3) * H_ + hb * 8 + (srow & 7);

    float acc[4][4];
#pragma unroll
    for (int a = 0; a < 4; ++a)
#pragma unroll
        for (int b = 0; b < 4; ++b) acc[a][b] = 0.0f;

    for (int cc = 0; cc < nchunks; ++cc) {
        const float* ap;
        const float* wp;
        if (layer == 0) {
            if (cc == 0) { ap = x + ((size_t)(bb * 32 + srow) * T_ + t) * I_; wp = Wih + grow * I_; }
            else         { ap = hprev + (bb * 32 + srow) * H_ + (cc - 1) * 128; wp = Whh + grow * H_ + (cc - 1) * 128; }
        } else {
            if (cc < 2)  { ap = h0cur + (bb * 32 + srow) * H_ + cc * 128;       wp = Wih + grow * H_ + cc * 128; }
            else         { ap = hprev + (bb * 32 + srow) * H_ + (cc - 2) * 128; wp = Whh + grow * H_ + (cc - 2) * 128; }
        }
#pragma unroll
        for (int i = 0; i < 4; ++i) {
            const int k4 = (kv + 8 * i) * 4;
            float4 va = *(const float4*)(ap + k4);
            As[(k4 + 0) * 36 + srow] = va.x;
            As[(k4 + 1) * 36 + srow] = va.y;
            As[(k4 + 2) * 36 + srow] = va.z;
            As[(k4 + 3) * 36 + srow] = va.w;
            float4 vw = *(const float4*)(wp + k4);
            Wsh[(k4 + 0) * 36 + srow] = vw.x;
            Wsh[(k4 + 1) * 36 + srow] = vw.y;
            Wsh[(k4 + 2) * 36 + srow] = vw.z;
            Wsh[(k4 + 3) * 36 + srow] = vw.w;
        }
        __syncthreads();
        const float* Ap = &As[(wave * 32) * 36 + br * 4];
        const float* Wp = &Wsh[(wave * 32) * 36 + gc8 * 4];
#pragma unroll
        for (int kk = 0; kk < 32; ++kk) {
            float4 a = *(const float4*)(Ap + kk * 36);
            float4 wv = *(const float4*)(Wp + kk * 36);
            acc[0][0] += a.x * wv.x; acc[0][1] += a.x * wv.y; acc[0][2] += a.x * wv.z; acc[0][3] += a.x * wv.w;
            acc[1][0] += a.y * wv.x; acc[1][1] += a.y * wv.y; acc[1][2] += a.y * wv.z; acc[1][3] += a.y * wv.w;
            acc[2][0] += a.z * wv.x; acc[2][1] += a.z * wv.y; acc[2][2] += a.z * wv.z; acc[2][3] += a.z * wv.w;
            acc[3][0] += a.w * wv.x; acc[3][1] += a.w * wv.y; acc[3][2] += a.w * wv.z; acc[3][3] += a.w * wv.w;
        }
        __syncthreads();
    }

    float* red = As;
    {
        const int base = tid * RSTR;
#pragma unroll
        for (int a = 0; a < 4; ++a)
#pragma unroll
            for (int b = 0; b < 4; ++b)
                red[base + a * 4 + b] = acc[a][b];
    }
    __syncthreads();
    {
        const int bl = tid >> 3;
        const int j = tid & 7;
        float g4[4];
#pragma unroll
        for (int g = 0; g < 4; ++g) {
            const int gc = g * 8 + j;
            const int br2 = bl >> 2, bi2 = bl & 3, gq = gc >> 2, gj = gc & 3;
            float v = 0.0f;
#pragma unroll
            for (int wv = 0; wv < 4; ++wv)
                v += red[(wv * 64 + br2 * 8 + gq) * RSTR + bi2 * 4 + gj];
            const int growg = g * H_ + hb * 8 + j;
            v += bi[growg] + bh[growg];
            g4[g] = v;
        }
        const float ig = fsig(g4[0]);
        const float fg = fsig(g4[1]);
        const float gg = ftanh(g4[2]);
        const float og = fsig(g4[3]);
        const int b = bb * 32 + bl;
        const int hidx = hb * 8 + j;
        const int ci = b * H_ + hidx;
        const float cn = fg * cbuf[ci] + ig * gg;
        cbuf[ci] = cn;
        hout[ci] = og * ftanh(cn);
    }
}

__global__ __launch_bounds__(256) void fc_kernel(
    const float* __restrict__ ws, const float* __restrict__ fcW,
    const float* __restrict__ fcb, float* __restrict__ out)
{
    __shared__ float As[128 * 36];
    __shared__ float Wsh[128 * 36];

    const float* h1 = ws + 3 * B_ * H_;
    const int bb = blockIdx.x >> 5;
    const int cb = blockIdx.x & 31;
    const int tid = threadIdx.x;
    const int srow = tid >> 3;
    const int kv = tid & 7;
    const int wave = tid >> 6;
    const int lane = tid & 63;
    const int br = lane >> 3;
    const int gc8 = lane & 7;
    const int crow = cb * 32 + srow;

    float acc[4][4];
#pragma unroll
    for (int a = 0; a < 4; ++a)
#pragma unroll
        for (int b = 0; b < 4; ++b) acc[a][b] = 0.0f;

    for (int cc = 0; cc < 2; ++cc) {
        const float* ap = h1 + (bb * 32 + srow) * H_ + cc * 128;
#pragma unroll
        for (int i = 0; i < 4; ++i) {
            const int k4 = (kv + 8 * i) * 4;
            float4 va = *(const float4*)(ap + k4);
            As[(k4 + 0) * 36 + srow] = va.x;
            As[(k4 + 1) * 36 + srow] = va.y;
            As[(k4 + 2) * 36 + srow] = va.z;
            As[(k4 + 3) * 36 + srow] = va.w;
            float4 vw = make_float4(0.f, 0.f, 0.f, 0.f);
            if (crow < C_) vw = *(const float4*)(fcW + crow * H_ + cc * 128 + k4);
            Wsh[(k4 + 0) * 36 + srow] = vw.x;
            Wsh[(k4 + 1) * 36 + srow] = vw.y;
            Wsh[(k4 + 2) * 36 + srow] = vw.z;
            Wsh[(k4 + 3) * 36 + srow] = vw.w;
        }
        __syncthreads();
        const float* Ap = &As[(wave * 32) * 36 + br * 4];
        const float* Wp = &Wsh[(wave * 32) * 36 + gc8 * 4];
#pragma unroll
        for (int kk = 0; kk < 32; ++kk) {
            float4 a = *(const float4*)(Ap + kk * 36);
            float4 wv = *(const float4*)(Wp + kk * 36);
            acc[0][0] += a.x * wv.x; acc[0][1] += a.x * wv.y; acc[0][2] += a.x * wv.z; acc[0][3] += a.x * wv.w;
            acc[1][0] += a.y * wv.x; acc[1][1] += a.y * wv.y; acc[1][2] += a.y * wv.z; acc[1][3] += a.y * wv.w;
            acc[2][0] += a.z * wv.x; acc[2][1] += a.z * wv.y; acc[2][2] += a.z * wv.z; acc[2][3] += a.z * wv.w;
            acc[3][0] += a.w * wv.x; acc[3][1] += a.w * wv.y; acc[3][2] += a.w * wv.z; acc[3][3] += a.w * wv.w;
        }
        __syncthreads();
    }

    float* red = As;
    {
        const int base = tid * RSTR;
#pragma unroll
        for (int a = 0; a < 4; ++a)
#pragma unroll
            for (int b = 0; b < 4; ++b)
                red[base + a * 4 + b] = acc[a][b];
    }
    __syncthreads();
    {
        const int bl = tid >> 3;
        const int j = tid & 7;
#pragma unroll
        for (int g = 0; g < 4; ++g) {
            const int gc = g * 8 + j;
            const int br2 = bl >> 2, bi2 = bl & 3, gq = gc >> 2, gj = gc & 3;
            float v = 0.0f;
#pragma unroll
            for (int wv = 0; wv < 4; ++wv)
                v += red[(wv * 64 + br2 * 8 + gq) * RSTR + bi2 * 4 + gj];
            const int cglob = cb * 32 + gc;
            if (cglob < C_) {
                v += fcb[cglob];
                out[(size_t)(bb * 32 + bl) * C_ + cglob] = v;
            }
        }
    }
}

extern "C" void kernel_launch(void* const* d_in, const int* in_sizes, int n_in,
                              void* d_out, int out_size, void* d_ws, size_t ws_size,
                              hipStream_t stream)
{
    const float* x    = (const float*)d_in[0];
    const float* Wih0 = (const float*)d_in[1];
    const float* Whh0 = (const float*)d_in[2];
    const float* bih0 = (const float*)d_in[3];
    const float* bhh0 = (const float*)d_in[4];
    const float* Wih1 = (const float*)d_in[5];
    const float* Whh1 = (const float*)d_in[6];
    const float* bih1 = (const float*)d_in[7];
    const float* bhh1 = (const float*)d_in[8];
    const float* fcW  = (const float*)d_in[9];
    const float* fcb  = (const float*)d_in[10];
    float* ws  = (float*)d_ws;
    float* out = (float*)d_out;

    // zero h0t[2], h1t[2], c0, c1 (ws is re-poisoned before every call)
    hipMemsetAsync(d_ws, 0, (size_t)6 * B_ * H_ * sizeof(float), stream);

    const bool use_t = ws_size >= (size_t)WS_NEED_FLOATS * sizeof(float);

    if (use_t) {
        transpose_w<<<WT_FLOATS / 256, 256, 0, stream>>>(Wih0, Whh0, Wih1, Whh1, ws);
        for (int s = 0; s <= T_; ++s) {
            lstm_step_t4<<<512, 256, 0, stream>>>(x, bih0, bhh0, bih1, bhh1, ws, s);
        }
        fc_kernel_t<<<256, 256, 0, stream>>>(ws, fcW, fcb, out);
    } else {
        for (int s = 0; s <= T_; ++s) {
            lstm_step<<<512, 256, 0, stream>>>(x, Wih0, Whh0, bih0, bhh0,
                                               Wih1, Whh1, bih1, bhh1, ws, s);
        }
        fc_kernel<<<256, 256, 0, stream>>>(ws, fcW, fcb, out);
    }
}

// Round 9
// 6584.511 us; speedup vs baseline: 1.1224x; 1.1224x over previous
//
#include <hip/hip_runtime.h>

#define B_ 256
#define T_ 512
#define I_ 128
#define H_ 256
#define C_ 1000

#define RSTR 17   // reduction row stride (floats), coprime to 32 banks

// workspace layout (floats):
//   0        h0t[2][H*B]   (TRANSPOSED hidden: ht[hidx][batch])
//   131072   h1t[2][H*B]
//   262144   c0[B*H]       (cell state, batch-major)
//   327680   c1[B*H]
//   393216   Wt_ih0 [128][1024]   (k-major transpose of Wih0)
//   524288   Wt_hh0 [256][1024]
//   786432   Wt_ih1 [256][1024]
//   1048576  Wt_hh1 [256][1024]
#define WT_OFF   393216
#define WT_FLOATS 917504
#define WS_NEED_FLOATS (WT_OFF + WT_FLOATS)

__device__ __forceinline__ float fsig(float x) { return 1.0f / (1.0f + __expf(-x)); }
__device__ __forceinline__ float ftanh(float x) { return 2.0f / (1.0f + __expf(-2.0f * x)) - 1.0f; }

// one-time: transpose the 4 weight matrices into k-major Wt[k][1024] (proven)
__global__ __launch_bounds__(256) void transpose_w(
    const float* __restrict__ Wih0, const float* __restrict__ Whh0,
    const float* __restrict__ Wih1, const float* __restrict__ Whh1,
    float* __restrict__ ws)
{
    int idx = blockIdx.x * 256 + threadIdx.x;
    float* wt = ws + WT_OFF;
    if (idx < 131072) { int k = idx >> 10, r = idx & 1023; wt[idx] = Wih0[r * I_ + k]; return; }
    idx -= 131072; wt += 131072;
    if (idx < 262144) { int k = idx >> 10, r = idx & 1023; wt[idx] = Whh0[r * H_ + k]; return; }
    idx -= 262144; wt += 262144;
    if (idx < 262144) { int k = idx >> 10, r = idx & 1023; wt[idx] = Wih1[r * H_ + k]; return; }
    idx -= 262144; wt += 262144;
    { int k = idx >> 10, r = idx & 1023; wt[idx] = Whh1[r * H_ + k]; }
}

// ---------------------------------------------------------------------------
// Per-step kernel v5 = r6's tile/staging/LDS geometry at 512 THREADS/block:
// 512 blocks x 512 threads -> 2 blocks/CU x 8 waves = 16 waves/CU (4/SIMD),
// doubling latency hiding (the r5/r6/r7 evidence says we're latency-bound,
// not DS/VALU-throughput-bound). K-split 8 (one 16-k window per wave),
// per-thread 4x4 tile; reduction sums the 8 wave-partials in sequential
// k order == r6's FP order -> absmax unchanged (0.0004882812).
// ---------------------------------------------------------------------------
__global__ __launch_bounds__(512) void lstm_step_t5(
    const float* __restrict__ x,
    const float* __restrict__ bih0, const float* __restrict__ bhh0,
    const float* __restrict__ bih1, const float* __restrict__ bhh1,
    float* __restrict__ ws, int s)
{
    __shared__ float lds[2 * 128 * 36];
    float* As  = lds;               // A: [k][36] (32 batches + pad)
    float* Wsh = lds + 128 * 36;    // W: [k][36] (32 gate cols + pad)

    float* h0t = ws;                 // [2][H*B] transposed
    float* h1t = ws + 2 * B_ * H_;   // [2][H*B] transposed
    float* c0 = ws + 4 * B_ * H_;
    float* c1 = ws + 5 * B_ * H_;

    const int w = blockIdx.x;
    const int layer = w >> 8;
    const int r = w & 255;
    const int bb = r >> 5;   // batch block (8 of 32)
    const int hb = r & 31;   // h block (32 of 8 h-indices -> 32 gate cols)

    if (layer == 0 && s >= T_) return;
    if (layer == 1 && s < 1) return;
    const int t = (layer == 0) ? s : (s - 1);

    const float* hprev_t; const float* h0cur_t = nullptr;
    float* hout_t; float* cbuf;
    const float* bi; const float* bh;
    const float* wt_ih; const float* wt_hh;
    int nchunks;
    if (layer == 0) {
        hprev_t = h0t + ((t - 1) & 1) * B_ * H_;
        hout_t  = h0t + (t & 1) * B_ * H_;
        cbuf = c0; bi = bih0; bh = bhh0;
        wt_ih = ws + WT_OFF;            // [128][1024]
        wt_hh = ws + WT_OFF + 131072;   // [256][1024]
        nchunks = 3;   // K = 128 (x) + 256 (h0prev)
    } else {
        h0cur_t = h0t + (t & 1) * B_ * H_;
        hprev_t = h1t + ((t - 1) & 1) * B_ * H_;
        hout_t  = h1t + (t & 1) * B_ * H_;
        cbuf = c1; bi = bih1; bh = bhh1;
        wt_ih = ws + WT_OFF + 393216;   // [256][1024]
        wt_hh = ws + WT_OFF + 655360;   // [256][1024]
        nchunks = 4;   // K = 256 (h0cur) + 256 (h1prev)
    }

    const int tid = threadIdx.x;          // 0..511
    const int wave = tid >> 6;            // 0..7
    const int lane = tid & 63;
    const int br = lane >> 3;             // batch quad 0..7 (batches br*4..+3)
    const int gc8 = lane & 7;             // col quad 0..7 (cols gc8*4..+3)
    const int kbase = wave * 16;          // this wave's 16-k window
    // fast staging map: 4 threads per k-row, 8 floats each
    const int krow = tid >> 2;            // 0..127
    const int q = tid & 3;                // 0..3
    // x-chunk scalar staging map: 16 threads per batch row
    const int srow = tid >> 4;            // 0..31
    const int kv = tid & 15;              // 0..15

    float acc[4][4];
#pragma unroll
    for (int a = 0; a < 4; ++a)
#pragma unroll
        for (int b = 0; b < 4; ++b) acc[a][b] = 0.0f;

    for (int cc = 0; cc < nchunks; ++cc) {
        // ---- stage A ----
        if (layer == 0 && cc == 0) {
            // x chunk: scalar transpose staging (2 float4 per thread)
            const float* ap = x + ((size_t)(bb * 32 + srow) * T_ + t) * I_;
#pragma unroll
            for (int i = 0; i < 2; ++i) {
                const int k4 = (kv + 16 * i) * 4;
                float4 va = *(const float4*)(ap + k4);
                As[(k4 + 0) * 36 + srow] = va.x;
                As[(k4 + 1) * 36 + srow] = va.y;
                As[(k4 + 2) * 36 + srow] = va.z;
                As[(k4 + 3) * 36 + srow] = va.w;
            }
        } else {
            // h chunk: k-major in ws -> straight b128 copy (2 float4 per thread)
            const float* hsrc; int k0;
            if (layer == 0) { hsrc = hprev_t; k0 = (cc - 1) * 128; }
            else if (cc < 2) { hsrc = h0cur_t; k0 = cc * 128; }
            else             { hsrc = hprev_t; k0 = (cc - 2) * 128; }
            const float* asrc = hsrc + (size_t)(k0 + krow) * B_ + bb * 32 + q * 8;
            float4 a0 = ((const float4*)asrc)[0];
            float4 a1 = ((const float4*)asrc)[1];
            float* adst = As + krow * 36 + q * 8;
            ((float4*)adst)[0] = a0;
            ((float4*)adst)[1] = a1;
        }
        // ---- stage W from k-major Wt (2 float4 per thread) ----
        {
            const float* wtc; int k0w;
            if (layer == 0) {
                if (cc == 0) { wtc = wt_ih; k0w = 0; }
                else         { wtc = wt_hh; k0w = (cc - 1) * 128; }
            } else {
                if (cc < 2)  { wtc = wt_ih; k0w = cc * 128; }
                else         { wtc = wt_hh; k0w = (cc - 2) * 128; }
            }
            // Wsh[k][g*8+j] = Wt[k0w+k][g*256 + hb*8 + j]; this thread: gate g=q
            const float* wsrc = wtc + (size_t)(k0w + krow) * 1024 + q * 256 + hb * 8;
            float4 w0 = ((const float4*)wsrc)[0];
            float4 w1 = ((const float4*)wsrc)[1];
            float* wdst = Wsh + krow * 36 + q * 8;
            ((float4*)wdst)[0] = w0;
            ((float4*)wdst)[1] = w1;
        }
        __syncthreads();
        // ---- compute: 4x4 per thread over this wave's 16-k window ----
        const float* Ap = &As[kbase * 36 + br * 4];
        const float* Wp = &Wsh[kbase * 36 + gc8 * 4];
#pragma unroll
        for (int kk = 0; kk < 16; ++kk) {
            float4 a = *(const float4*)(Ap + kk * 36);
            float4 wv = *(const float4*)(Wp + kk * 36);
            acc[0][0] += a.x * wv.x; acc[0][1] += a.x * wv.y; acc[0][2] += a.x * wv.z; acc[0][3] += a.x * wv.w;
            acc[1][0] += a.y * wv.x; acc[1][1] += a.y * wv.y; acc[1][2] += a.y * wv.z; acc[1][3] += a.y * wv.w;
            acc[2][0] += a.z * wv.x; acc[2][1] += a.z * wv.y; acc[2][2] += a.z * wv.z; acc[2][3] += a.z * wv.w;
            acc[3][0] += a.w * wv.x; acc[3][1] += a.w * wv.y; acc[3][2] += a.w * wv.z; acc[3][3] += a.w * wv.w;
        }
        __syncthreads();
    }

    // cross-wave reduction: 8 sequential 16-k partials per output (== r6 FP order)
    float* red = lds;   // 512*17 = 8704 <= 9216 floats
    {
        const int base = tid * RSTR;
#pragma unroll
        for (int a = 0; a < 4; ++a)
#pragma unroll
            for (int b = 0; b < 4; ++b)
                red[base + a * 4 + b] = acc[a][b];
    }
    __syncthreads();
    if (tid < 256) {
        const int bl = tid >> 3;  // local batch 0..31
        const int j = tid & 7;    // local h-index 0..7
        float g4[4];
#pragma unroll
        for (int g = 0; g < 4; ++g) {
            const int gc = g * 8 + j;                       // local gate col
            const int br2 = bl >> 2, bi2 = bl & 3, gq = gc >> 2, gj = gc & 3;
            float v = 0.0f;
#pragma unroll
            for (int wv = 0; wv < 8; ++wv)
                v += red[(wv * 64 + br2 * 8 + gq) * RSTR + bi2 * 4 + gj];
            const int growg = g * H_ + hb * 8 + j;
            v += bi[growg] + bh[growg];
            g4[g] = v;
        }
        const float ig = fsig(g4[0]);
        const float fg = fsig(g4[1]);
        const float gg = ftanh(g4[2]);
        const float og = fsig(g4[3]);
        const int b = bb * 32 + bl;
        const int hidx = hb * 8 + j;
        const int ci = b * H_ + hidx;             // c stays batch-major
        const float cn = fg * cbuf[ci] + ig * gg;
        cbuf[ci] = cn;
        hout_t[(size_t)hidx * B_ + b] = og * ftanh(cn);   // h stored TRANSPOSED
    }
}

// fc over transposed h1: h1t[hidx][batch] (verbatim r4-proven)
__global__ __launch_bounds__(256) void fc_kernel_t(
    const float* __restrict__ ws, const float* __restrict__ fcW,
    const float* __restrict__ fcb, float* __restrict__ out)
{
    __shared__ float As[128 * 36];
    __shared__ float Wsh[128 * 36];

    const float* h1 = ws + 3 * B_ * H_;  // h1t[(T-1)&1] = h1t[1]
    const int bb = blockIdx.x >> 5;
    const int cb = blockIdx.x & 31;
    const int tid = threadIdx.x;
    const int srow = tid >> 3;
    const int kv = tid & 7;
    const int wave = tid >> 6;
    const int lane = tid & 63;
    const int br = lane >> 3;
    const int gc8 = lane & 7;
    const int crow = cb * 32 + srow;
    const int krow = tid >> 1;
    const int half = tid & 1;

    float acc[4][4];
#pragma unroll
    for (int a = 0; a < 4; ++a)
#pragma unroll
        for (int b = 0; b < 4; ++b) acc[a][b] = 0.0f;

    for (int cc = 0; cc < 2; ++cc) {
        {
            const float* asrc = h1 + (size_t)(cc * 128 + krow) * B_ + bb * 32 + half * 16;
            float4 a0 = ((const float4*)asrc)[0];
            float4 a1 = ((const float4*)asrc)[1];
            float4 a2 = ((const float4*)asrc)[2];
            float4 a3 = ((const float4*)asrc)[3];
            float* adst = As + krow * 36 + half * 16;
            ((float4*)adst)[0] = a0;
            ((float4*)adst)[1] = a1;
            ((float4*)adst)[2] = a2;
            ((float4*)adst)[3] = a3;
        }
#pragma unroll
        for (int i = 0; i < 4; ++i) {
            const int k4 = (kv + 8 * i) * 4;
            float4 vw = make_float4(0.f, 0.f, 0.f, 0.f);
            if (crow < C_) vw = *(const float4*)(fcW + crow * H_ + cc * 128 + k4);
            Wsh[(k4 + 0) * 36 + srow] = vw.x;
            Wsh[(k4 + 1) * 36 + srow] = vw.y;
            Wsh[(k4 + 2) * 36 + srow] = vw.z;
            Wsh[(k4 + 3) * 36 + srow] = vw.w;
        }
        __syncthreads();
        const float* Ap = &As[(wave * 32) * 36 + br * 4];
        const float* Wp = &Wsh[(wave * 32) * 36 + gc8 * 4];
#pragma unroll
        for (int kk = 0; kk < 32; ++kk) {
            float4 a = *(const float4*)(Ap + kk * 36);
            float4 wv = *(const float4*)(Wp + kk * 36);
            acc[0][0] += a.x * wv.x; acc[0][1] += a.x * wv.y; acc[0][2] += a.x * wv.z; acc[0][3] += a.x * wv.w;
            acc[1][0] += a.y * wv.x; acc[1][1] += a.y * wv.y; acc[1][2] += a.y * wv.z; acc[1][3] += a.y * wv.w;
            acc[2][0] += a.z * wv.x; acc[2][1] += a.z * wv.y; acc[2][2] += a.z * wv.z; acc[2][3] += a.z * wv.w;
            acc[3][0] += a.w * wv.x; acc[3][1] += a.w * wv.y; acc[3][2] += a.w * wv.z; acc[3][3] += a.w * wv.w;
        }
        __syncthreads();
    }

    float* red = As;
    {
        const int base = tid * RSTR;
#pragma unroll
        for (int a = 0; a < 4; ++a)
#pragma unroll
            for (int b = 0; b < 4; ++b)
                red[base + a * 4 + b] = acc[a][b];
    }
    __syncthreads();
    {
        const int bl = tid >> 3;
        const int j = tid & 7;
#pragma unroll
        for (int g = 0; g < 4; ++g) {
            const int gc = g * 8 + j;
            const int br2 = bl >> 2, bi2 = bl & 3, gq = gc >> 2, gj = gc & 3;
            float v = 0.0f;
#pragma unroll
            for (int wv = 0; wv < 4; ++wv)
                v += red[(wv * 64 + br2 * 8 + gq) * RSTR + bi2 * 4 + gj];
            const int cglob = cb * 32 + gc;
            if (cglob < C_) {
                v += fcb[cglob];
                out[(size_t)(bb * 32 + bl) * C_ + cglob] = v;
            }
        }
    }
}

// ---------------------------------------------------------------------------
// Fallback pair (proven 7472us path, batch-major h) if ws is too small.
// ---------------------------------------------------------------------------
__global__ __launch_bounds__(256) void lstm_step(
    const float* __restrict__ x,
    const float* __restrict__ Wih0, const float* __restrict__ Whh0,
    const float* __restrict__ bih0, const float* __restrict__ bhh0,
    const float* __restrict__ Wih1, const float* __restrict__ Whh1,
    const float* __restrict__ bih1, const float* __restrict__ bhh1,
    float* __restrict__ ws, int s)
{
    __shared__ float As[128 * 36];
    __shared__ float Wsh[128 * 36];

    float* h0buf = ws;
    float* h1buf = ws + 2 * B_ * H_;
    float* c0 = ws + 4 * B_ * H_;
    float* c1 = ws + 5 * B_ * H_;

    const int w = blockIdx.x;
    const int layer = w >> 8;
    const int r = w & 255;
    const int bb = r >> 5;
    const int hb = r & 31;

    if (layer == 0 && s >= T_) return;
    if (layer == 1 && s < 1) return;
    const int t = (layer == 0) ? s : (s - 1);

    const float* hprev; const float* h0cur = nullptr;
    float* hout; float* cbuf;
    const float* Wih; const float* Whh; const float* bi; const float* bh;
    int nchunks;
    if (layer == 0) {
        hprev = h0buf + ((t - 1) & 1) * B_ * H_;
        hout  = h0buf + (t & 1) * B_ * H_;
        cbuf = c0; Wih = Wih0; Whh = Whh0; bi = bih0; bh = bhh0;
        nchunks = 3;
    } else {
        h0cur = h0buf + (t & 1) * B_ * H_;
        hprev = h1buf + ((t - 1) & 1) * B_ * H_;
        hout  = h1buf + (t & 1) * B_ * H_;
        cbuf = c1; Wih = Wih1; Whh = Whh1; bi = bih1; bh = bhh1;
        nchunks = 4;
    }

    const int tid = threadIdx.x;
    const int srow = tid >> 3;
    const int kv = tid & 7;
    const int wave = tid >> 6;
    const int lane = tid & 63;
    const int br = lane >> 3;
    const int gc8 = lane & 7;
    const int grow = (srow >> 3) * H_ + hb * 8 + (srow & 7);

    float acc[4][4];
#pragma unroll
    for (int a = 0; a < 4; ++a)
#pragma unroll
        for (int b = 0; b < 4; ++b) acc[a][b] = 0.0f;

    for (int cc = 0; cc < nchunks; ++cc) {
        const float* ap;
        const float* wp;
        if (layer == 0) {
            if (cc == 0) { ap = x + ((size_t)(bb * 32 + srow) * T_ + t) * I_; wp = Wih + grow * I_; }
            else         { ap = hprev + (bb * 32 + srow) * H_ + (cc - 1) * 128; wp = Whh + grow * H_ + (cc - 1) * 128; }
        } else {
            if (cc < 2)  { ap = h0cur + (bb * 32 + srow) * H_ + cc * 128;       wp = Wih + grow * H_ + cc * 128; }
            else         { ap = hprev + (bb * 32 + srow) * H_ + (cc - 2) * 128; wp = Whh + grow * H_ + (cc - 2) * 128; }
        }
#pragma unroll
        for (int i = 0; i < 4; ++i) {
            const int k4 = (kv + 8 * i) * 4;
            float4 va = *(const float4*)(ap + k4);
            As[(k4 + 0) * 36 + srow] = va.x;
            As[(k4 + 1) * 36 + srow] = va.y;
            As[(k4 + 2) * 36 + srow] = va.z;
            As[(k4 + 3) * 36 + srow] = va.w;
            float4 vw = *(const float4*)(wp + k4);
            Wsh[(k4 + 0) * 36 + srow] = vw.x;
            Wsh[(k4 + 1) * 36 + srow] = vw.y;
            Wsh[(k4 + 2) * 36 + srow] = vw.z;
            Wsh[(k4 + 3) * 36 + srow] = vw.w;
        }
        __syncthreads();
        const float* Ap = &As[(wave * 32) * 36 + br * 4];
        const float* Wp = &Wsh[(wave * 32) * 36 + gc8 * 4];
#pragma unroll
        for (int kk = 0; kk < 32; ++kk) {
            float4 a = *(const float4*)(Ap + kk * 36);
            float4 wv = *(const float4*)(Wp + kk * 36);
            acc[0][0] += a.x * wv.x; acc[0][1] += a.x * wv.y; acc[0][2] += a.x * wv.z; acc[0][3] += a.x * wv.w;
            acc[1][0] += a.y * wv.x; acc[1][1] += a.y * wv.y; acc[1][2] += a.y * wv.z; acc[1][3] += a.y * wv.w;
            acc[2][0] += a.z * wv.x; acc[2][1] += a.z * wv.y; acc[2][2] += a.z * wv.z; acc[2][3] += a.z * wv.w;
            acc[3][0] += a.w * wv.x; acc[3][1] += a.w * wv.y; acc[3][2] += a.w * wv.z; acc[3][3] += a.w * wv.w;
        }
        __syncthreads();
    }

    float* red = As;
    {
        const int base = tid * RSTR;
#pragma unroll
        for (int a = 0; a < 4; ++a)
#pragma unroll
            for (int b = 0; b < 4; ++b)
                red[base + a * 4 + b] = acc[a][b];
    }
    __syncthreads();
    {
        const int bl = tid >> 3;
        const int j = tid & 7;
        float g4[4];
#pragma unroll
        for (int g = 0; g < 4; ++g) {
            const int gc = g * 8 + j;
            const int br2 = bl >> 2, bi2 = bl & 3, gq = gc >> 2, gj = gc & 3;
            float v = 0.0f;
#pragma unroll
            for (int wv = 0; wv < 4; ++wv)
                v += red[(wv * 64 + br2 * 8 + gq) * RSTR + bi2 * 4 + gj];
            const int growg = g * H_ + hb * 8 + j;
            v += bi[growg] + bh[growg];
            g4[g] = v;
        }
        const float ig = fsig(g4[0]);
        const float fg = fsig(g4[1]);
        const float gg = ftanh(g4[2]);
        const float og = fsig(g4[3]);
        const int b = bb * 32 + bl;
        const int hidx = hb * 8 + j;
        const int ci = b * H_ + hidx;
        const float cn = fg * cbuf[ci] + ig * gg;
        cbuf[ci] = cn;
        hout[ci] = og * ftanh(cn);
    }
}

__global__ __launch_bounds__(256) void fc_kernel(
    const float* __restrict__ ws, const float* __restrict__ fcW,
    const float* __restrict__ fcb, float* __restrict__ out)
{
    __shared__ float As[128 * 36];
    __shared__ float Wsh[128 * 36];

    const float* h1 = ws + 3 * B_ * H_;
    const int bb = blockIdx.x >> 5;
    const int cb = blockIdx.x & 31;
    const int tid = threadIdx.x;
    const int srow = tid >> 3;
    const int kv = tid & 7;
    const int wave = tid >> 6;
    const int lane = tid & 63;
    const int br = lane >> 3;
    const int gc8 = lane & 7;
    const int crow = cb * 32 + srow;

    float acc[4][4];
#pragma unroll
    for (int a = 0; a < 4; ++a)
#pragma unroll
        for (int b = 0; b < 4; ++b) acc[a][b] = 0.0f;

    for (int cc = 0; cc < 2; ++cc) {
        const float* ap = h1 + (bb * 32 + srow) * H_ + cc * 128;
#pragma unroll
        for (int i = 0; i < 4; ++i) {
            const int k4 = (kv + 8 * i) * 4;
            float4 va = *(const float4*)(ap + k4);
            As[(k4 + 0) * 36 + srow] = va.x;
            As[(k4 + 1) * 36 + srow] = va.y;
            As[(k4 + 2) * 36 + srow] = va.z;
            As[(k4 + 3) * 36 + srow] = va.w;
            float4 vw = make_float4(0.f, 0.f, 0.f, 0.f);
            if (crow < C_) vw = *(const float4*)(fcW + crow * H_ + cc * 128 + k4);
            Wsh[(k4 + 0) * 36 + srow] = vw.x;
            Wsh[(k4 + 1) * 36 + srow] = vw.y;
            Wsh[(k4 + 2) * 36 + srow] = vw.z;
            Wsh[(k4 + 3) * 36 + srow] = vw.w;
        }
        __syncthreads();
        const float* Ap = &As[(wave * 32) * 36 + br * 4];
        const float* Wp = &Wsh[(wave * 32) * 36 + gc8 * 4];
#pragma unroll
        for (int kk = 0; kk < 32; ++kk) {
            float4 a = *(const float4*)(Ap + kk * 36);
            float4 wv = *(const float4*)(Wp + kk * 36);
            acc[0][0] += a.x * wv.x; acc[0][1] += a.x * wv.y; acc[0][2] += a.x * wv.z; acc[0][3] += a.x * wv.w;
            acc[1][0] += a.y * wv.x; acc[1][1] += a.y * wv.y; acc[1][2] += a.y * wv.z; acc[1][3] += a.y * wv.w;
            acc[2][0] += a.z * wv.x; acc[2][1] += a.z * wv.y; acc[2][2] += a.z * wv.z; acc[2][3] += a.z * wv.w;
            acc[3][0] += a.w * wv.x; acc[3][1] += a.w * wv.y; acc[3][2] += a.w * wv.z; acc[3][3] += a.w * wv.w;
        }
        __syncthreads();
    }

    float* red = As;
    {
        const int base = tid * RSTR;
#pragma unroll
        for (int a = 0; a < 4; ++a)
#pragma unroll
            for (int b = 0; b < 4; ++b)
                red[base + a * 4 + b] = acc[a][b];
    }
    __syncthreads();
    {
        const int bl = tid >> 3;
        const int j = tid & 7;
#pragma unroll
        for (int g = 0; g < 4; ++g) {
            const int gc = g * 8 + j;
            const int br2 = bl >> 2, bi2 = bl & 3, gq = gc >> 2, gj = gc & 3;
            float v = 0.0f;
#pragma unroll
            for (int wv = 0; wv < 4; ++wv)
                v += red[(wv * 64 + br2 * 8 + gq) * RSTR + bi2 * 4 + gj];
            const int cglob = cb * 32 + gc;
            if (cglob < C_) {
                v += fcb[cglob];
                out[(size_t)(bb * 32 + bl) * C_ + cglob] = v;
            }
        }
    }
}

extern "C" void kernel_launch(void* const* d_in, const int* in_sizes, int n_in,
                              void* d_out, int out_size, void* d_ws, size_t ws_size,
                              hipStream_t stream)
{
    const float* x    = (const float*)d_in[0];
    const float* Wih0 = (const float*)d_in[1];
    const float* Whh0 = (const float*)d_in[2];
    const float* bih0 = (const float*)d_in[3];
    const float* bhh0 = (const float*)d_in[4];
    const float* Wih1 = (const float*)d_in[5];
    const float* Whh1 = (const float*)d_in[6];
    const float* bih1 = (const float*)d_in[7];
    const float* bhh1 = (const float*)d_in[8];
    const float* fcW  = (const float*)d_in[9];
    const float* fcb  = (const float*)d_in[10];
    float* ws  = (float*)d_ws;
    float* out = (float*)d_out;

    // zero h0t[2], h1t[2], c0, c1 (ws is re-poisoned before every call)
    hipMemsetAsync(d_ws, 0, (size_t)6 * B_ * H_ * sizeof(float), stream);

    const bool use_t = ws_size >= (size_t)WS_NEED_FLOATS * sizeof(float);

    if (use_t) {
        transpose_w<<<WT_FLOATS / 256, 256, 0, stream>>>(Wih0, Whh0, Wih1, Whh1, ws);
        for (int s = 0; s <= T_; ++s) {
            lstm_step_t5<<<512, 512, 0, stream>>>(x, bih0, bhh0, bih1, bhh1, ws, s);
        }
        fc_kernel_t<<<256, 256, 0, stream>>>(ws, fcW, fcb, out);
    } else {
        for (int s = 0; s <= T_; ++s) {
            lstm_step<<<512, 256, 0, stream>>>(x, Wih0, Whh0, bih0, bhh0,
                                               Wih1, Whh1, bih1, bhh1, ws, s);
        }
        fc_kernel<<<256, 256, 0, stream>>>(ws, fcW, fcb, out);
    }
}